// Round 3
// baseline (544.196 us; speedup 1.0000x reference)
//
#include <hip/hip_runtime.h>
#include <hip/hip_bf16.h>

typedef short short8 __attribute__((ext_vector_type(8)));
typedef float f32x4 __attribute__((ext_vector_type(4)));

#define T_ 512
#define B_ 1024
#define D_ 128
#define H_ 64
#define A_ 18
#define TB_ (T_*B_)

// ws layout (ushort units): [x_actor | x_critic | bf16 weights]
// scan overwrites x[t] slice with h[t] (same shape) -> head kernel reads h there.
#define XELEMS (TB_*H_)          // 33554432 per branch
#define WBASE  (2*XELEMS)
#define WBR    38912             // per-branch weight elems
#define W1OFF  0
#define W2OFF  8192
#define WIHOFF 12288
#define WHHOFF 24576
#define WHDOFF 36864

// out layout (floats): logits | values | actor_state | critic_state
#define LOGN  (TB_*A_)           // 9437184
#define VOFF_ LOGN
#define SOFF_ (LOGN + TB_)       // 9961472

__device__ __forceinline__ ushort f2bf(float f) {
  __hip_bfloat16 h = __float2bfloat16(f);
  return __builtin_bit_cast(ushort, h);
}
__device__ __forceinline__ int cvt_pk_bf16(float lo, float hi) {
  int r;
  asm("v_cvt_pk_bf16_f32 %0, %1, %2" : "=v"(r) : "v"(lo), "v"(hi));
  return r;
}
__device__ __forceinline__ float sigm(float x) {
  float e = __builtin_amdgcn_exp2f(-1.44269504f * x);
  return __builtin_amdgcn_rcpf(1.0f + e);
}
__device__ __forceinline__ float tanh_(float x) {
  float e = __builtin_amdgcn_exp2f(-2.88539008f * x);
  return 2.0f * __builtin_amdgcn_rcpf(1.0f + e) - 1.0f;
}

__global__ __launch_bounds__(256) void prep_kernel(
    const float* aW1, const float* aW2, const float* aWih, const float* aWhh, const float* aWl,
    const float* cW1, const float* cW2, const float* cWih, const float* cWhh, const float* cWv,
    ushort* wts) {
  int idx = blockIdx.x * 256 + threadIdx.x;
  if (idx >= 2*WBR) return;
  int br = idx / WBR, off = idx % WBR;
  float v;
  if      (off < W2OFF)  v = (br ? cW1  : aW1 )[off];
  else if (off < WIHOFF) v = (br ? cW2  : aW2 )[off - W2OFF];
  else if (off < WHHOFF) v = (br ? cWih : aWih)[off - WIHOFF];
  else if (off < WHDOFF) v = (br ? cWhh : aWhh)[off - WHHOFF];
  else {
    int t = off - WHDOFF;
    if (br == 0) v = (t < A_*H_) ? aWl[t] : 0.f;
    else         v = (t < H_)    ? cWv[t] : 0.f;
  }
  wts[WBASE + idx] = f2bf(v);
}

// ---------------- phase 1: fused MLP, barrier-free, x -> ws (bf16, swizzled) ----------
__global__ __launch_bounds__(256) void mlp_kernel(
    const float* __restrict__ obs, const ushort* __restrict__ wts,
    const float* __restrict__ ab1, const float* __restrict__ ab2,
    const float* __restrict__ cb1, const float* __restrict__ cb2,
    ushort* __restrict__ xout) {
  __shared__ __align__(16) ushort htmp[4][16 * H_];   // per-wave 2KB, wave-local only
  const int tid = threadIdx.x;
  const int l = tid & 63, w = tid >> 6;
  const int lr = l & 15, lg = l >> 4;
  const int key = lr & 7;
  const long r0 = (long)blockIdx.x * 64;
  const long row = r0 + w * 16 + lr;
  const f32x4 fzero = {0.f, 0.f, 0.f, 0.f};

  // A-fragments of obs for this lane's row (reused by both branches), packed via cvt_pk
  short8 af[4];
  {
    const float* op = obs + row * D_;
    #pragma unroll
    for (int ks = 0; ks < 4; ++ks) {
      float4 f0 = *(const float4*)(op + ks * 32 + lg * 8);
      float4 f1 = *(const float4*)(op + ks * 32 + lg * 8 + 4);
      int4 u;
      u.x = cvt_pk_bf16(f0.x, f0.y);
      u.y = cvt_pk_bf16(f0.z, f0.w);
      u.z = cvt_pk_bf16(f1.x, f1.y);
      u.w = cvt_pk_bf16(f1.z, f1.w);
      af[ks] = __builtin_bit_cast(short8, u);
    }
  }

  #pragma unroll 1
  for (int br = 0; br < 2; ++br) {
    const ushort* wb = wts + WBASE + br * WBR;
    const float* b1 = br ? cb1 : ab1;
    const float* b2 = br ? cb2 : ab2;

    // ---- layer 1: [16,128] @ [128,64]
    f32x4 acc[4];
    #pragma unroll
    for (int nt = 0; nt < 4; ++nt) acc[nt] = fzero;
    #pragma unroll
    for (int ks = 0; ks < 4; ++ks) {
      #pragma unroll
      for (int nt = 0; nt < 4; ++nt) {
        int n = nt * 16 + lr;
        short8 b = *(const short8*)(wb + W1OFF + n * D_ + ks * 32 + lg * 8);
        acc[nt] = __builtin_amdgcn_mfma_f32_16x16x32_bf16(af[ks], b, acc[nt], 0, 0, 0);
      }
    }
    // bias+relu -> htmp[w] (swizzled), wave-local
    #pragma unroll
    for (int nt = 0; nt < 4; ++nt) {
      int coln = nt * 16 + lr;
      float bias = b1[coln];
      #pragma unroll
      for (int j = 0; j < 4; ++j) {
        int rw = lg * 4 + j;
        float v = fmaxf(acc[nt][j] + bias, 0.f);
        int idx = rw * H_ + ((((coln >> 3) ^ (rw & 7))) << 3) + (coln & 7);
        htmp[w][idx] = f2bf(v);
      }
    }
    // ---- layer 2: [16,64] @ [64,64]  (wave-local ds round-trip, no barrier)
    short8 a2[2];
    #pragma unroll
    for (int ks = 0; ks < 2; ++ks) {
      int c = ks * 4 + lg;
      a2[ks] = *(const short8*)(&htmp[w][lr * H_ + ((c ^ key) << 3)]);
    }
    f32x4 acc2[4];
    #pragma unroll
    for (int nt = 0; nt < 4; ++nt) acc2[nt] = fzero;
    #pragma unroll
    for (int ks = 0; ks < 2; ++ks) {
      #pragma unroll
      for (int nt = 0; nt < 4; ++nt) {
        int n = nt * 16 + lr;
        short8 b = *(const short8*)(wb + W2OFF + n * H_ + ks * 32 + lg * 8);
        acc2[nt] = __builtin_amdgcn_mfma_f32_16x16x32_bf16(a2[ks], b, acc2[nt], 0, 0, 0);
      }
    }
    #pragma unroll
    for (int nt = 0; nt < 4; ++nt) {
      int coln = nt * 16 + lr;
      float bias = b2[coln];
      #pragma unroll
      for (int j = 0; j < 4; ++j) {
        int rw = lg * 4 + j;
        float v = fmaxf(acc2[nt][j] + bias, 0.f);
        int idx = rw * H_ + ((((coln >> 3) ^ (rw & 7))) << 3) + (coln & 7);
        htmp[w][idx] = f2bf(v);
      }
    }
    // coalesced copy of this wave's 2KB slice (swizzle embedded) -> global x
    {
      const uint4* sp = (const uint4*)(&htmp[w][0]);
      uint4* dp = (uint4*)(xout + (size_t)br * XELEMS + (size_t)(r0 + w * 16) * H_);
      dp[l * 2]     = sp[l * 2];
      dp[l * 2 + 1] = sp[l * 2 + 1];
    }
  }
}

// ---------------- phase 2: GRU scan (no heads, h history written in-place over x) -----
__global__ __launch_bounds__(256, 1) void scan_kernel(
    ushort* __restrict__ ws,            // x at 0 (overwritten by h), weights at WBASE
    const float* __restrict__ dones,
    const float* __restrict__ astate, const float* __restrict__ cstate,
    const float* __restrict__ abih, const float* __restrict__ abhh,
    const float* __restrict__ cbih, const float* __restrict__ cbhh,
    float* __restrict__ out) {
  __shared__ __align__(16) ushort hbuf[2][16 * H_];
  __shared__ __align__(16) float  dlds[T_ * 16];     // all dones for this slice (32KB)
  const int tid = threadIdx.x;
  const int l = tid & 63, w = tid >> 6;
  const int lr = l & 15, lg = l >> 4;
  const int br = blockIdx.x & 1;
  const int b0 = (blockIdx.x >> 1) * 16;
  const int key = lr & 7;
  const f32x4 fzero = {0.f, 0.f, 0.f, 0.f};

  const ushort* wb = ws + WBASE + br * WBR;
  ushort* xp = ws + (size_t)br * XELEMS;
  const float* bihp = br ? cbih : abih;
  const float* bhhp = br ? cbhh : abhh;
  const float* st   = br ? cstate : astate;

  // dones -> LDS (one-time)
  #pragma unroll
  for (int i = 0; i < 8; ++i) {
    int s = tid + i * 256;              // 2048 float4 slots
    int t = s >> 2, p = s & 3;
    *(float4*)(dlds + t * 16 + p * 4) = *(const float4*)(dones + (size_t)t * B_ + b0 + p * 4);
  }

  // persistent weight B-fragments
  short8 ihB[3][2], hhB[3][2];
  #pragma unroll
  for (int g = 0; g < 3; ++g) {
    int n = g * 64 + w * 16 + lr;
    #pragma unroll
    for (int ks = 0; ks < 2; ++ks) {
      ihB[g][ks] = *(const short8*)(wb + WIHOFF + n * H_ + ks * 32 + lg * 8);
      hhB[g][ks] = *(const short8*)(wb + WHHOFF + n * H_ + ks * 32 + lg * 8);
    }
  }

  float bs0, bs1, bin, bhn;
  {
    int o0 = w * 16 + lr;
    bs0 = bihp[o0] + bhhp[o0];
    bs1 = bihp[64 + o0] + bhhp[64 + o0];
    bin = bihp[128 + o0];
    bhn = bhhp[128 + o0];
  }

  const int coln = w * 16 + lr;

  auto loadx = [&](int t, short8 (&f)[2]) {
    size_t rowe = ((size_t)t * B_ + b0 + lr) * H_;
    #pragma unroll
    for (int ks = 0; ks < 2; ++ks) {
      int c = ks * 4 + lg;
      f[ks] = *(const short8*)(xp + rowe + ((c ^ key) << 3));
    }
  };

  short8 buf0[2], buf1[2], buf2[2], buf3[2];
  loadx(0, buf0); loadx(1, buf1); loadx(2, buf2); loadx(3, buf3);

  // h init (fp32 persistent regs: rows lg*4+j, col w*16+lr); reset with done_0
  float h_old[4];
  #pragma unroll
  for (int j = 0; j < 4; ++j)
    h_old[j] = st[(size_t)(b0 + lg * 4 + j) * H_ + w * 16 + lr];

  __syncthreads();   // dlds visible

  #pragma unroll
  for (int j = 0; j < 4; ++j) {
    if (dlds[lg * 4 + j] != 0.f) h_old[j] = 0.f;
    int rw = lg * 4 + j;
    int idx = rw * H_ + ((((coln >> 3) ^ (rw & 7))) << 3) + (coln & 7);
    hbuf[0][idx] = f2bf(h_old[j]);
  }

  asm volatile("s_waitcnt lgkmcnt(0)" ::: "memory");
  __builtin_amdgcn_s_barrier();

  int cur = 0;

  auto dostep = [&](int t, short8 (&xb)[2]) {
    // h_{t-1} fragments from LDS (already reset-applied at write time)
    short8 hf0 = *(const short8*)(&hbuf[cur][lr * H_ + (((0 + lg) ^ key) << 3)]);
    short8 hf1 = *(const short8*)(&hbuf[cur][lr * H_ + (((4 + lg) ^ key) << 3)]);
    // done_{t+1} for this lane's 4 rows (b128 from LDS); masked off on last step
    int tn = t + 1;
    float4 dnv = *(const float4*)(&dlds[((tn < T_) ? tn : 0) * 16 + lg * 4]);
    bool tv = (tn < T_);

    // gi = x@Wih^T (independent of h; overlaps ds_read latency)
    f32x4 gi0 = fzero, gi1 = fzero, gi2 = fzero;
    gi0 = __builtin_amdgcn_mfma_f32_16x16x32_bf16(xb[0], ihB[0][0], gi0, 0, 0, 0);
    gi0 = __builtin_amdgcn_mfma_f32_16x16x32_bf16(xb[1], ihB[0][1], gi0, 0, 0, 0);
    gi1 = __builtin_amdgcn_mfma_f32_16x16x32_bf16(xb[0], ihB[1][0], gi1, 0, 0, 0);
    gi1 = __builtin_amdgcn_mfma_f32_16x16x32_bf16(xb[1], ihB[1][1], gi1, 0, 0, 0);
    gi2 = __builtin_amdgcn_mfma_f32_16x16x32_bf16(xb[0], ihB[2][0], gi2, 0, 0, 0);
    gi2 = __builtin_amdgcn_mfma_f32_16x16x32_bf16(xb[1], ihB[2][1], gi2, 0, 0, 0);
    // gh split into two independent accumulators (no 2-deep MFMA chain)
    f32x4 ga0 = fzero, ga1 = fzero, ga2 = fzero, gb0 = fzero, gb1 = fzero, gb2 = fzero;
    ga0 = __builtin_amdgcn_mfma_f32_16x16x32_bf16(hf0, hhB[0][0], ga0, 0, 0, 0);
    gb0 = __builtin_amdgcn_mfma_f32_16x16x32_bf16(hf1, hhB[0][1], gb0, 0, 0, 0);
    ga1 = __builtin_amdgcn_mfma_f32_16x16x32_bf16(hf0, hhB[1][0], ga1, 0, 0, 0);
    gb1 = __builtin_amdgcn_mfma_f32_16x16x32_bf16(hf1, hhB[1][1], gb1, 0, 0, 0);
    ga2 = __builtin_amdgcn_mfma_f32_16x16x32_bf16(hf0, hhB[2][0], ga2, 0, 0, 0);
    gb2 = __builtin_amdgcn_mfma_f32_16x16x32_bf16(hf1, hhB[2][1], gb2, 0, 0, 0);

    // prefetch t+4 into the buffer just consumed (loads BEFORE any stores this step)
    int tp = (t + 4 < T_) ? t + 4 : T_ - 1;
    loadx(tp, xb);

    // gates + h-history store + LDS write (reset applied with done_{t+1})
    int nxt = cur ^ 1;
    #pragma unroll
    for (int j = 0; j < 4; ++j) {
      float r = sigm(gi0[j] + ga0[j] + gb0[j] + bs0);
      float z = sigm(gi1[j] + ga1[j] + gb1[j] + bs1);
      float n = tanh_((gi2[j] + bin) + r * (ga2[j] + gb2[j] + bhn));
      float hn = n + z * (h_old[j] - n);
      ushort hb = f2bf(hn);
      int rw = lg * 4 + j;
      // h history (pre-reset) in-place over x[t]
      xp[((size_t)t * B_ + b0 + rw) * H_ + coln] = hb;
      // reset for next step
      bool rs = tv && (dnv[j] != 0.f);
      h_old[j] = rs ? 0.f : hn;
      ushort hbr = rs ? (ushort)0 : hb;
      int idx = rw * H_ + ((((coln >> 3) ^ (rw & 7))) << 3) + (coln & 7);
      hbuf[nxt][idx] = hbr;
    }
    asm volatile("s_waitcnt lgkmcnt(0)" ::: "memory");
    __builtin_amdgcn_s_barrier();
    cur = nxt;
  };

  for (int it = 0; it < T_ / 4; ++it) {
    dostep(4 * it,     buf0);
    dostep(4 * it + 1, buf1);
    dostep(4 * it + 2, buf2);
    dostep(4 * it + 3, buf3);
  }

  // final states (fp32; last step applied no reset since tn==T_)
  #pragma unroll
  for (int j = 0; j < 4; ++j) {
    size_t off = SOFF_ + (size_t)br * (B_ * H_) + (size_t)(b0 + lg * 4 + j) * H_ + w * 16 + lr;
    out[off] = h_old[j];
  }
}

// ---------------- phase 3: heads (logits + values) from h history ---------------------
__global__ __launch_bounds__(256) void head_kernel(
    const ushort* __restrict__ ws,
    const float* __restrict__ abl, const float* __restrict__ cbv,
    float* __restrict__ out) {
  const int tid = threadIdx.x;
  const int l = tid & 63, w = tid >> 6;
  const int lr = l & 15, lg = l >> 4;
  const long r0 = (long)blockIdx.x * 64 + w * 16;   // TB-row base for this wave
  const f32x4 fzero = {0.f, 0.f, 0.f, 0.f};

  // actor h A-frags
  const ushort* hA = ws + r0 * H_;
  const ushort* hC = ws + XELEMS + r0 * H_;
  short8 aA[2], aC[2];
  #pragma unroll
  for (int ks = 0; ks < 2; ++ks) {
    aA[ks] = *(const short8*)(hA + lr * H_ + ks * 32 + lg * 8);
    aC[ks] = *(const short8*)(hC + lr * H_ + ks * 32 + lg * 8);
  }
  // logits: [16,64]@[64,32] (Wl zero-padded to 32 rows)
  const ushort* wbA = ws + WBASE + WHDOFF;
  const ushort* wbC = ws + WBASE + WBR + WHDOFF;
  f32x4 acc[2];
  acc[0] = fzero; acc[1] = fzero;
  #pragma unroll
  for (int nt = 0; nt < 2; ++nt) {
    int n = nt * 16 + lr;
    #pragma unroll
    for (int ks = 0; ks < 2; ++ks) {
      short8 b = *(const short8*)(wbA + n * H_ + ks * 32 + lg * 8);
      acc[nt] = __builtin_amdgcn_mfma_f32_16x16x32_bf16(aA[ks], b, acc[nt], 0, 0, 0);
    }
  }
  // values: [16,64]@[64,16] (only n==0 nonzero)
  f32x4 vacc = fzero;
  {
    int n = lr;
    #pragma unroll
    for (int ks = 0; ks < 2; ++ks) {
      short8 b = *(const short8*)(wbC + n * H_ + ks * 32 + lg * 8);
      vacc = __builtin_amdgcn_mfma_f32_16x16x32_bf16(aC[ks], b, vacc, 0, 0, 0);
    }
  }
  // stores
  #pragma unroll
  for (int nt = 0; nt < 2; ++nt) {
    int n = nt * 16 + lr;
    if (n < A_) {
      float bias = abl[n];
      #pragma unroll
      for (int j = 0; j < 4; ++j)
        out[(r0 + lg * 4 + j) * A_ + n] = acc[nt][j] + bias;
    }
  }
  if (lr == 0) {
    float bias = cbv[0];
    #pragma unroll
    for (int j = 0; j < 4; ++j)
      out[VOFF_ + r0 + lg * 4 + j] = vacc[j] + bias;
  }
}

extern "C" void kernel_launch(void* const* d_in, const int* in_sizes, int n_in,
                              void* d_out, int out_size, void* d_ws, size_t ws_size,
                              hipStream_t stream) {
  const float* obs    = (const float*)d_in[0];
  const float* dones  = (const float*)d_in[1];
  const float* astate = (const float*)d_in[2];
  const float* cstate = (const float*)d_in[3];
  const float* aW1  = (const float*)d_in[4];
  const float* ab1  = (const float*)d_in[5];
  const float* aW2  = (const float*)d_in[6];
  const float* ab2  = (const float*)d_in[7];
  const float* aWih = (const float*)d_in[8];
  const float* aWhh = (const float*)d_in[9];
  const float* abih = (const float*)d_in[10];
  const float* abhh = (const float*)d_in[11];
  const float* aWl  = (const float*)d_in[12];
  const float* abl  = (const float*)d_in[13];
  const float* cW1  = (const float*)d_in[14];
  const float* cb1  = (const float*)d_in[15];
  const float* cW2  = (const float*)d_in[16];
  const float* cb2  = (const float*)d_in[17];
  const float* cWih = (const float*)d_in[18];
  const float* cWhh = (const float*)d_in[19];
  const float* cbih = (const float*)d_in[20];
  const float* cbhh = (const float*)d_in[21];
  const float* cWv  = (const float*)d_in[22];
  const float* cbv  = (const float*)d_in[23];
  ushort* ws = (ushort*)d_ws;
  float* out = (float*)d_out;

  const size_t need = ((size_t)2 * XELEMS + 2 * WBR) * 2;
  if (ws_size < need) {
    hipMemsetAsync(d_out, 0x7F, 16, stream);
    return;
  }

  hipLaunchKernelGGL(prep_kernel, dim3(304), dim3(256), 0, stream,
                     aW1, aW2, aWih, aWhh, aWl, cW1, cW2, cWih, cWhh, cWv, ws);
  hipLaunchKernelGGL(mlp_kernel, dim3(TB_ / 64), dim3(256), 0, stream,
                     obs, ws, ab1, ab2, cb1, cb2, ws);
  hipLaunchKernelGGL(scan_kernel, dim3(128), dim3(256), 0, stream,
                     ws, dones, astate, cstate, abih, abhh, cbih, cbhh, out);
  hipLaunchKernelGGL(head_kernel, dim3(TB_ / 64), dim3(256), 0, stream,
                     ws, abl, cbv, out);
}

// Round 4
// 492.786 us; speedup vs baseline: 1.1043x; 1.1043x over previous
//
#include <hip/hip_runtime.h>
#include <hip/hip_bf16.h>

typedef short short8 __attribute__((ext_vector_type(8)));
typedef float f32x4 __attribute__((ext_vector_type(4)));

#define T_ 512
#define B_ 1024
#define D_ 128
#define H_ 64
#define A_ 18
#define TB_ (T_*B_)

// ws layout (ushort units): [x_actor | x_critic | bf16 weights]
// x is PLAIN row-major [T][B][H]. scan overwrites x[t] with h[t] (row-major).
#define XELEMS (TB_*H_)          // 33554432 per branch
#define WBASE  (2*XELEMS)
#define WBR    38912             // per-branch weight elems
#define W1OFF  0
#define W2OFF  8192
#define WIHOFF 12288
#define WHHOFF 24576
#define WHDOFF 36864

// out layout (floats): logits | values | actor_state | critic_state
#define LOGN  (TB_*A_)           // 9437184
#define VOFF_ LOGN
#define SOFF_ (LOGN + TB_)       // 9961472

#define S1_ (-1.4426950408889634f)   // -log2(e)   (r,z gates)
#define S2_ (-2.885390081777927f)    // -2*log2(e) (n gate)

__device__ __forceinline__ ushort f2bf(float f) {
  __hip_bfloat16 h = __float2bfloat16(f);
  return __builtin_bit_cast(ushort, h);
}
__device__ __forceinline__ uint cvt_pk_bf16(float lo, float hi) {
  uint r;
  asm("v_cvt_pk_bf16_f32 %0, %1, %2" : "=v"(r) : "v"(lo), "v"(hi));
  return r;
}

__global__ __launch_bounds__(256) void prep_kernel(
    const float* aW1, const float* aW2, const float* aWih, const float* aWhh, const float* aWl,
    const float* cW1, const float* cW2, const float* cWih, const float* cWhh, const float* cWv,
    ushort* wts) {
  int idx = blockIdx.x * 256 + threadIdx.x;
  if (idx >= 2*WBR) return;
  int br = idx / WBR, off = idx % WBR;
  float v;
  if      (off < W2OFF)  v = (br ? cW1  : aW1 )[off];
  else if (off < WIHOFF) v = (br ? cW2  : aW2 )[off - W2OFF];
  else if (off < WHHOFF) {
    int rel = off - WIHOFF;
    v = (br ? cWih : aWih)[rel];
    v *= (rel < 128*H_) ? S1_ : S2_;      // fold gate logistic scales
  }
  else if (off < WHDOFF) {
    int rel = off - WHHOFF;
    v = (br ? cWhh : aWhh)[rel];
    v *= (rel < 128*H_) ? S1_ : S2_;
  }
  else {
    int t = off - WHDOFF;
    if (br == 0) v = (t < A_*H_) ? aWl[t] : 0.f;
    else         v = (t < H_)    ? cWv[t] : 0.f;
  }
  wts[WBASE + idx] = f2bf(v);
}

// ---------------- phase 1: fused MLP, barrier-free, x -> ws (bf16, PLAIN row-major) ---
__global__ __launch_bounds__(256) void mlp_kernel(
    const float* __restrict__ obs, const ushort* __restrict__ wts,
    const float* __restrict__ ab1, const float* __restrict__ ab2,
    const float* __restrict__ cb1, const float* __restrict__ cb2,
    ushort* __restrict__ xout) {
  __shared__ __align__(16) ushort htmp[4][16 * H_];   // per-wave 2KB, wave-local only
  const int tid = threadIdx.x;
  const int l = tid & 63, w = tid >> 6;
  const int lr = l & 15, lg = l >> 4;
  const int key = lr & 7;
  const long r0 = (long)blockIdx.x * 64;
  const long row = r0 + w * 16 + lr;
  const f32x4 fzero = {0.f, 0.f, 0.f, 0.f};

  // A-fragments of obs for this lane's row (reused by both branches)
  short8 af[4];
  {
    const float* op = obs + row * D_;
    #pragma unroll
    for (int ks = 0; ks < 4; ++ks) {
      float4 f0 = *(const float4*)(op + ks * 32 + lg * 8);
      float4 f1 = *(const float4*)(op + ks * 32 + lg * 8 + 4);
      uint4 u;
      u.x = cvt_pk_bf16(f0.x, f0.y);
      u.y = cvt_pk_bf16(f0.z, f0.w);
      u.z = cvt_pk_bf16(f1.x, f1.y);
      u.w = cvt_pk_bf16(f1.z, f1.w);
      af[ks] = __builtin_bit_cast(short8, u);
    }
  }

  #pragma unroll 1
  for (int br = 0; br < 2; ++br) {
    const ushort* wb = wts + WBASE + br * WBR;
    const float* b1 = br ? cb1 : ab1;
    const float* b2 = br ? cb2 : ab2;

    // ---- layer 1: [16,128] @ [128,64]
    f32x4 acc[4];
    #pragma unroll
    for (int nt = 0; nt < 4; ++nt) acc[nt] = fzero;
    #pragma unroll
    for (int ks = 0; ks < 4; ++ks) {
      #pragma unroll
      for (int nt = 0; nt < 4; ++nt) {
        int n = nt * 16 + lr;
        short8 b = *(const short8*)(wb + W1OFF + n * D_ + ks * 32 + lg * 8);
        acc[nt] = __builtin_amdgcn_mfma_f32_16x16x32_bf16(af[ks], b, acc[nt], 0, 0, 0);
      }
    }
    // bias+relu -> htmp[w] (16B-unit swizzle, key=row&7), wave-local
    #pragma unroll
    for (int nt = 0; nt < 4; ++nt) {
      int coln = nt * 16 + lr;
      float bias = b1[coln];
      #pragma unroll
      for (int j = 0; j < 4; ++j) {
        int rw = lg * 4 + j;
        float v = fmaxf(acc[nt][j] + bias, 0.f);
        int idx = rw * H_ + ((((coln >> 3) ^ (rw & 7))) << 3) + (coln & 7);
        htmp[w][idx] = f2bf(v);
      }
    }
    // ---- layer 2: [16,64] @ [64,64]  (wave-local ds round-trip, no barrier)
    short8 a2[2];
    #pragma unroll
    for (int ks = 0; ks < 2; ++ks) {
      int c = ks * 4 + lg;
      a2[ks] = *(const short8*)(&htmp[w][lr * H_ + ((c ^ key) << 3)]);
    }
    f32x4 acc2[4];
    #pragma unroll
    for (int nt = 0; nt < 4; ++nt) acc2[nt] = fzero;
    #pragma unroll
    for (int ks = 0; ks < 2; ++ks) {
      #pragma unroll
      for (int nt = 0; nt < 4; ++nt) {
        int n = nt * 16 + lr;
        short8 b = *(const short8*)(wb + W2OFF + n * H_ + ks * 32 + lg * 8);
        acc2[nt] = __builtin_amdgcn_mfma_f32_16x16x32_bf16(a2[ks], b, acc2[nt], 0, 0, 0);
      }
    }
    #pragma unroll
    for (int nt = 0; nt < 4; ++nt) {
      int coln = nt * 16 + lr;
      float bias = b2[coln];
      #pragma unroll
      for (int j = 0; j < 4; ++j) {
        int rw = lg * 4 + j;
        float v = fmaxf(acc2[nt][j] + bias, 0.f);
        int idx = rw * H_ + ((((coln >> 3) ^ (rw & 7))) << 3) + (coln & 7);
        htmp[w][idx] = f2bf(v);
      }
    }
    // de-swizzling copy: htmp[w] -> global x, PLAIN row-major
    {
      ushort* dp = xout + (size_t)br * XELEMS + (size_t)(r0 + w * 16) * H_;
      #pragma unroll
      for (int i = 0; i < 2; ++i) {
        int id = l + i * 64;          // 128 chunks of 16B
        int rr = id >> 3, cc = id & 7;
        uint4 v = *(const uint4*)(&htmp[w][rr * H_ + ((cc ^ (rr & 7)) << 3)]);
        *(uint4*)(dp + rr * H_ + (cc << 3)) = v;
      }
    }
  }
}

// ---------------- phase 2: GRU scan (swapped-operand MFMA; h history row-major) -------
__global__ __launch_bounds__(256, 1) void scan_kernel(
    const ushort* __restrict__ wts,     // ws + WBASE region
    const ushort* __restrict__ xin,     // ws x region (load-only view)
    ushort* __restrict__ hist,          // ws x region (store-only view; t-disjoint)
    const float* __restrict__ dones,
    const float* __restrict__ astate, const float* __restrict__ cstate,
    const float* __restrict__ abih, const float* __restrict__ abhh,
    const float* __restrict__ cbih, const float* __restrict__ cbhh,
    float* __restrict__ out) {
  __shared__ __align__(16) ushort hbuf[2][16 * H_];  // h^T tiles, 16B-unit swizzled
  __shared__ __align__(16) float  dlds[T_ * 16];     // all dones for this slice (32KB)
  const int tid = threadIdx.x;
  const int l = tid & 63, w = tid >> 6;
  const int lr = l & 15, lg = l >> 4;
  const int br = blockIdx.x & 1;
  const int b0 = (blockIdx.x >> 1) * 16;
  const f32x4 fzero = {0.f, 0.f, 0.f, 0.f};

  const ushort* wb = wts + br * WBR;
  const ushort* xp = xin + (size_t)br * XELEMS;
  ushort* hp = hist + (size_t)br * XELEMS;
  const float* bihp = br ? cbih : abih;
  const float* bhhp = br ? cbhh : abhh;
  const float* st   = br ? cstate : astate;

  // dones -> LDS (one-time)
  #pragma unroll
  for (int i = 0; i < 8; ++i) {
    int s = tid + i * 256;              // 2048 float4 slots
    int t = s >> 2, p = s & 3;
    *(float4*)(dlds + t * 16 + p * 4) = *(const float4*)(dones + (size_t)t * B_ + b0 + p * 4);
  }

  // persistent weight A-fragments (row = gate-col, k = h-col) — plain row-major bytes
  short8 ihA[3][2], hhA[3][2];
  #pragma unroll
  for (int g = 0; g < 3; ++g) {
    int n = g * 64 + w * 16 + lr;
    #pragma unroll
    for (int ks = 0; ks < 2; ++ks) {
      ihA[g][ks] = *(const short8*)(wb + WIHOFF + n * H_ + ks * 32 + lg * 8);
      hhA[g][ks] = *(const short8*)(wb + WHHOFF + n * H_ + ks * 32 + lg * 8);
    }
  }

  // biases for this lane's 4 gate-cols (scaled to match prescaled weights)
  const int o4 = w * 16 + lg * 4;
  f32x4 bs0, bs1, binv, bhnv;
  {
    float4 a0 = *(const float4*)(bihp + o4),       h0v = *(const float4*)(bhhp + o4);
    float4 a1 = *(const float4*)(bihp + 64 + o4),  h1v = *(const float4*)(bhhp + 64 + o4);
    float4 a2 = *(const float4*)(bihp + 128 + o4), h2v = *(const float4*)(bhhp + 128 + o4);
    bs0[0]=S1_*(a0.x+h0v.x); bs0[1]=S1_*(a0.y+h0v.y); bs0[2]=S1_*(a0.z+h0v.z); bs0[3]=S1_*(a0.w+h0v.w);
    bs1[0]=S1_*(a1.x+h1v.x); bs1[1]=S1_*(a1.y+h1v.y); bs1[2]=S1_*(a1.z+h1v.z); bs1[3]=S1_*(a1.w+h1v.w);
    binv[0]=S2_*a2.x; binv[1]=S2_*a2.y; binv[2]=S2_*a2.z; binv[3]=S2_*a2.w;
    bhnv[0]=S2_*h2v.x; bhnv[1]=S2_*h2v.y; bhnv[2]=S2_*h2v.z; bhnv[3]=S2_*h2v.w;
  }

  // hbuf addressing (ushort units). write: 8B half-unit; read: 16B unit, XOR key lr&7
  const int myW = lr * H_ + (((w * 2 + (lg >> 1)) ^ (lr & 7)) << 3) + (lg & 1) * 4;
  const int rdA = lr * H_ + (((0 * 4 + lg) ^ (lr & 7)) << 3);
  const int rdB = lr * H_ + (((1 * 4 + lg) ^ (lr & 7)) << 3);

  // h init: lane holds (batch b0+lr, cols o4..o4+3), fp32
  float h_old[4];
  {
    float4 h0v = *(const float4*)(st + (size_t)(b0 + lr) * H_ + o4);
    float dn0 = dones[b0 + lr];
    bool rs0 = (dn0 != 0.f);
    h_old[0] = rs0 ? 0.f : h0v.x; h_old[1] = rs0 ? 0.f : h0v.y;
    h_old[2] = rs0 ? 0.f : h0v.z; h_old[3] = rs0 ? 0.f : h0v.w;
    uint2 hv;
    hv.x = cvt_pk_bf16(h_old[0], h_old[1]);
    hv.y = cvt_pk_bf16(h_old[2], h_old[3]);
    *(uint2*)(&hbuf[0][myW]) = hv;
  }

  __syncthreads();   // dlds + hbuf[0] visible

  auto loadx = [&](int t, short8 (&f)[2]) {
    const ushort* p = xp + ((size_t)t * B_ + b0 + lr) * H_;
    f[0] = *(const short8*)(p + lg * 8);
    f[1] = *(const short8*)(p + 32 + lg * 8);
  };

  short8 buf0[2], buf1[2], buf2[2], buf3[2];
  loadx(0, buf0); loadx(1, buf1); loadx(2, buf2); loadx(3, buf3);

  int cur = 0;

  auto dostep = [&](int t, short8 (&xb)[2]) {
    // h^T fragments (B-operand) from LDS
    short8 hf0 = *(const short8*)(&hbuf[cur][rdA]);
    short8 hf1 = *(const short8*)(&hbuf[cur][rdB]);
    // done_{t+1} for this lane's batch row
    int tn = t + 1;
    float dn = dlds[((tn < T_) ? tn : 0) * 16 + lr];
    bool rs = (tn < T_) && (dn != 0.f);

    // gi = Wih · x^T  (x prefetched; off critical path — chained accumulate)
    f32x4 gi0 = fzero, gi1 = fzero, gi2 = fzero;
    gi0 = __builtin_amdgcn_mfma_f32_16x16x32_bf16(ihA[0][0], xb[0], gi0, 0, 0, 0);
    gi0 = __builtin_amdgcn_mfma_f32_16x16x32_bf16(ihA[0][1], xb[1], gi0, 0, 0, 0);
    gi1 = __builtin_amdgcn_mfma_f32_16x16x32_bf16(ihA[1][0], xb[0], gi1, 0, 0, 0);
    gi1 = __builtin_amdgcn_mfma_f32_16x16x32_bf16(ihA[1][1], xb[1], gi1, 0, 0, 0);
    gi2 = __builtin_amdgcn_mfma_f32_16x16x32_bf16(ihA[2][0], xb[0], gi2, 0, 0, 0);
    gi2 = __builtin_amdgcn_mfma_f32_16x16x32_bf16(ihA[2][1], xb[1], gi2, 0, 0, 0);
    // gh = Whh · h^T  (split accumulators; no dependent MFMA chain on hf)
    f32x4 ga0 = fzero, ga1 = fzero, ga2 = fzero, gb0 = fzero, gb1 = fzero, gb2 = fzero;
    ga0 = __builtin_amdgcn_mfma_f32_16x16x32_bf16(hhA[0][0], hf0, ga0, 0, 0, 0);
    gb0 = __builtin_amdgcn_mfma_f32_16x16x32_bf16(hhA[0][1], hf1, gb0, 0, 0, 0);
    ga1 = __builtin_amdgcn_mfma_f32_16x16x32_bf16(hhA[1][0], hf0, ga1, 0, 0, 0);
    gb1 = __builtin_amdgcn_mfma_f32_16x16x32_bf16(hhA[1][1], hf1, gb1, 0, 0, 0);
    ga2 = __builtin_amdgcn_mfma_f32_16x16x32_bf16(hhA[2][0], hf0, ga2, 0, 0, 0);
    gb2 = __builtin_amdgcn_mfma_f32_16x16x32_bf16(hhA[2][1], hf1, gb2, 0, 0, 0);

    // prefetch t+4 into the consumed buffer (restrict: never ordered vs h stores)
    int tp = (t + 4 < T_) ? t + 4 : T_ - 1;
    loadx(tp, xb);

    // gates (weights prescaled: sigm = rcp(1+exp2(s)); tanh = 2*rcp(1+exp2(s))-1)
    float hn[4];
    #pragma unroll
    for (int j = 0; j < 4; ++j) {
      float sr = gi0[j] + ga0[j] + gb0[j] + bs0[j];
      float rr = __builtin_amdgcn_rcpf(1.f + __builtin_amdgcn_exp2f(sr));
      float sz = gi1[j] + ga1[j] + gb1[j] + bs1[j];
      float zz = __builtin_amdgcn_rcpf(1.f + __builtin_amdgcn_exp2f(sz));
      float tg = ga2[j] + gb2[j] + bhnv[j];
      float sn = fmaf(rr, tg, gi2[j] + binv[j]);
      float qq = __builtin_amdgcn_rcpf(1.f + __builtin_amdgcn_exp2f(sn));
      float nn = fmaf(2.f, qq, -1.f);
      hn[j] = fmaf(zz, h_old[j] - nn, nn);
    }
    // h history (pre-reset), packed row-major dwordx2 — fully coalesced
    uint2 hv;
    hv.x = cvt_pk_bf16(hn[0], hn[1]);
    hv.y = cvt_pk_bf16(hn[2], hn[3]);
    *(uint2*)(hp + ((size_t)t * B_ + b0 + lr) * H_ + o4) = hv;
    // reset with done_{t+1}; write h_t to other buffer
    uint2 hz;
    hz.x = rs ? 0u : hv.x;
    hz.y = rs ? 0u : hv.y;
    h_old[0] = rs ? 0.f : hn[0]; h_old[1] = rs ? 0.f : hn[1];
    h_old[2] = rs ? 0.f : hn[2]; h_old[3] = rs ? 0.f : hn[3];
    int nxt = cur ^ 1;
    *(uint2*)(&hbuf[nxt][myW]) = hz;
    asm volatile("s_waitcnt lgkmcnt(0)" ::: "memory");
    __builtin_amdgcn_s_barrier();
    cur = nxt;
  };

  for (int it = 0; it < T_ / 4; ++it) {
    dostep(4 * it,     buf0);
    dostep(4 * it + 1, buf1);
    dostep(4 * it + 2, buf2);
    dostep(4 * it + 3, buf3);
  }

  // final states (fp32, post step 511; no reset applied on last step)
  float4 fs = {h_old[0], h_old[1], h_old[2], h_old[3]};
  *(float4*)(out + SOFF_ + (size_t)br * (B_ * H_) + (size_t)(b0 + lr) * H_ + o4) = fs;
}

// ---------------- phase 3: heads (logits + values) from row-major h history -----------
__global__ __launch_bounds__(256) void head_kernel(
    const ushort* __restrict__ ws,
    const float* __restrict__ abl, const float* __restrict__ cbv,
    float* __restrict__ out) {
  const int tid = threadIdx.x;
  const int l = tid & 63, w = tid >> 6;
  const int lr = l & 15, lg = l >> 4;
  const long r0 = (long)blockIdx.x * 64 + w * 16;   // TB-row base for this wave
  const f32x4 fzero = {0.f, 0.f, 0.f, 0.f};

  const ushort* hA = ws + r0 * H_;
  const ushort* hC = ws + XELEMS + r0 * H_;
  short8 aA[2], aC[2];
  #pragma unroll
  for (int ks = 0; ks < 2; ++ks) {
    aA[ks] = *(const short8*)(hA + lr * H_ + ks * 32 + lg * 8);
    aC[ks] = *(const short8*)(hC + lr * H_ + ks * 32 + lg * 8);
  }
  // logits: [16,64]@[64,32] (Wl zero-padded to 32 rows)
  const ushort* wbA = ws + WBASE + WHDOFF;
  const ushort* wbC = ws + WBASE + WBR + WHDOFF;
  f32x4 acc[2];
  acc[0] = fzero; acc[1] = fzero;
  #pragma unroll
  for (int nt = 0; nt < 2; ++nt) {
    int n = nt * 16 + lr;
    #pragma unroll
    for (int ks = 0; ks < 2; ++ks) {
      short8 b = *(const short8*)(wbA + n * H_ + ks * 32 + lg * 8);
      acc[nt] = __builtin_amdgcn_mfma_f32_16x16x32_bf16(aA[ks], b, acc[nt], 0, 0, 0);
    }
  }
  // values: [16,64]@[64,16] (only n==0 nonzero)
  f32x4 vacc = fzero;
  {
    int n = lr;
    #pragma unroll
    for (int ks = 0; ks < 2; ++ks) {
      short8 b = *(const short8*)(wbC + n * H_ + ks * 32 + lg * 8);
      vacc = __builtin_amdgcn_mfma_f32_16x16x32_bf16(aC[ks], b, vacc, 0, 0, 0);
    }
  }
  // stores
  #pragma unroll
  for (int nt = 0; nt < 2; ++nt) {
    int n = nt * 16 + lr;
    if (n < A_) {
      float bias = abl[n];
      #pragma unroll
      for (int j = 0; j < 4; ++j)
        out[(r0 + lg * 4 + j) * A_ + n] = acc[nt][j] + bias;
    }
  }
  if (lr == 0) {
    float bias = cbv[0];
    #pragma unroll
    for (int j = 0; j < 4; ++j)
      out[VOFF_ + r0 + lg * 4 + j] = vacc[j] + bias;
  }
}

extern "C" void kernel_launch(void* const* d_in, const int* in_sizes, int n_in,
                              void* d_out, int out_size, void* d_ws, size_t ws_size,
                              hipStream_t stream) {
  const float* obs    = (const float*)d_in[0];
  const float* dones  = (const float*)d_in[1];
  const float* astate = (const float*)d_in[2];
  const float* cstate = (const float*)d_in[3];
  const float* aW1  = (const float*)d_in[4];
  const float* ab1  = (const float*)d_in[5];
  const float* aW2  = (const float*)d_in[6];
  const float* ab2  = (const float*)d_in[7];
  const float* aWih = (const float*)d_in[8];
  const float* aWhh = (const float*)d_in[9];
  const float* abih = (const float*)d_in[10];
  const float* abhh = (const float*)d_in[11];
  const float* aWl  = (const float*)d_in[12];
  const float* abl  = (const float*)d_in[13];
  const float* cW1  = (const float*)d_in[14];
  const float* cb1  = (const float*)d_in[15];
  const float* cW2  = (const float*)d_in[16];
  const float* cb2  = (const float*)d_in[17];
  const float* cWih = (const float*)d_in[18];
  const float* cWhh = (const float*)d_in[19];
  const float* cbih = (const float*)d_in[20];
  const float* cbhh = (const float*)d_in[21];
  const float* cWv  = (const float*)d_in[22];
  const float* cbv  = (const float*)d_in[23];
  ushort* ws = (ushort*)d_ws;
  float* out = (float*)d_out;

  const size_t need = ((size_t)2 * XELEMS + 2 * WBR) * 2;
  if (ws_size < need) {
    hipMemsetAsync(d_out, 0x7F, 16, stream);
    return;
  }

  hipLaunchKernelGGL(prep_kernel, dim3(304), dim3(256), 0, stream,
                     aW1, aW2, aWih, aWhh, aWl, cW1, cW2, cWih, cWhh, cWv, ws);
  hipLaunchKernelGGL(mlp_kernel, dim3(TB_ / 64), dim3(256), 0, stream,
                     obs, ws, ab1, ab2, cb1, cb2, ws);
  hipLaunchKernelGGL(scan_kernel, dim3(128), dim3(256), 0, stream,
                     ws + WBASE, ws, ws, dones, astate, cstate,
                     abih, abhh, cbih, cbhh, out);
  hipLaunchKernelGGL(head_kernel, dim3(TB_ / 64), dim3(256), 0, stream,
                     ws, abl, cbv, out);
}